// Round 19
// baseline (119.362 us; speedup 1.0000x reference)
//
#include <hip/hip_runtime.h>
#include <math.h>

// CapsuleLayer dynamic routing. B=256, IN=1152, K=8, J=10, D=16, 3 passes.
//
// 5 kernels; global reduction via device-scope memory-side f32 atomicAdd.
// Lessons ledger: grid.sync ~100us/sync (r8); threadfence ~50us/pass (r12);
// UC-atomic slabs ~30us/pass (r13); kernel boundary ~1us (r13 calib);
// launch_bounds must not squeeze VGPR below ~84 need (r16: (256,4)->64;
// r18: (512,4)->64 -> 28MB/pass spill); NSLAB*IPB==IN_CAPS (r15);
// per-block fixed costs scale with block count (r17: 2x blocks regressed).
//  prep_all : (r7-r14-verified) W -> wht bf16 [i][jd][k]*0.25 (k-replication
//             trick: 4 K-quads read the same 8-k fragment -> u = 4*(x*W/4));
//             x -> xht bf16 [i][b][k]. Zeroes s_sum0.
//  caps_pass<P>: grid (96 i-slabs x 8 b-groups) = 768 blocks x 512 thr,
//             launch_bounds(512,2) -> VGPR free (~80, no spill), LDS 43KB
//             -> 3 blocks/CU = 24 waves/CU (2x r14 TLP). Block covers
//             12 i x 32 b; wave w = (half h=w>>2: 16-batch subtile,
//             quarter r=w&3: 3 i). W slab staged ONCE per block ->
//             23.6MB/pass (half of r14). P>0 preamble: redundant squash
//             of s_sum for 32 batches -> vdl (16-lane shfl; P2 adds
//             v0+v1). Compute = r11-verified MFMA fragment math +
//             in-lane softmax (no max-sub). Per-half 4-wave LDS tree
//             reduce; r==0 waves atomicAdd into s_sum[jd][b].
//             islab==0 zeroes next s_sum.
//  sq_final : squash s_sum2 -> out.
// FP-atomic order varies run-to-run (~1e-6) — tolerance-validated.
// Algebra: logits at pass t = (sum of previous v)·u_hat; pass 0 c = 0.1.

typedef float f32x4 __attribute__((ext_vector_type(4)));
typedef short bf16x8 __attribute__((ext_vector_type(8)));

#define B_TOT 256
#define IN_CAPS 1152
#define OUT_CAPS 10
#define JD 160

#define NSLAB 96
#define IPB 12             // i per block  (NSLAB*IPB == IN_CAPS == 1152)
#define BPB 32             // batches per block
#define THREADS 512
#define REDS 164

// LDS: [wsl 30720 B][xsl 12288 B] = 43008; red (41984) / vdl (20992) alias.
#define XSL_OFF_B 30720
#define SMEM_B 43008

#define WHT_BYTES (1152ull * 160 * 8 * 2)             // 2,949,120
#define XHT_BYTES (1152ull * 256 * 8 * 2)             // 4,718,592
#define SSUM_BYTES ((size_t)B_TOT * JD * 4)           // 163,840
#define WS_NEED   (WHT_BYTES + XHT_BYTES + 3 * SSUM_BYTES)

static __device__ __forceinline__ unsigned f2bf(float f) {
    unsigned u = __float_as_uint(f);
    return (u + 0x7FFFu + ((u >> 16) & 1u)) >> 16;
}

// ---------------- coalesced preps (r7-r14-verified) ----------------
#define PREPW_BLOCKS 288   // 4 i each
#define PREPX_BLOCKS 288   // 16 i x 64 b each

__global__ __launch_bounds__(256)
void prep_all(const float* __restrict__ x, const float* __restrict__ W,
              unsigned* __restrict__ whu, unsigned* __restrict__ xhu,
              float* __restrict__ s0) {
    __shared__ __align__(16) float lds[64 * 132];   // 33,792 B
    const int bid = blockIdx.x, t = threadIdx.x;

    if (bid < 160) s0[bid * 256 + t] = 0.f;         // zero s_sum0 (replay-safe)

    if (bid < PREPW_BLOCKS) {
        const int i0 = bid * 4;
        const f32x4* src = (const f32x4*)(W + (size_t)i0 * 1280);
        for (int c = t; c < 1280; c += 256)
            *(f32x4*)(lds + c * 4) = src[c];          // coalesced read
        __syncthreads();
        for (int c = t; c < 2560; c += 256) {
            const int i_l = c / 640, p = c % 640;
            const int jd = p >> 2, kp = p & 3;        // k = 2*kp
            const int j = jd >> 4, d = jd & 15;
            const float* base = lds + i_l * 1280 + j * 128 + d;
            const unsigned lo = f2bf(base[(2 * kp) * 16] * 0.25f);
            const unsigned hi = f2bf(base[(2 * kp + 1) * 16] * 0.25f);
            whu[(size_t)i0 * 640 + c] = lo | (hi << 16);   // coalesced write
        }
    } else {
        const int bx = bid - PREPW_BLOCKS;
        const int it = bx >> 2;          // 72 i-tiles
        const int bt = bx & 3;           // 4 b-tiles of 64
        const int i0 = it * 16, b0 = bt * 64;
        for (int c = t; c < 2048; c += 256) {
            const int bl = c >> 5, cf = c & 31;
            f32x4 v = *(const f32x4*)(x + (size_t)(b0 + bl) * 9216 + i0 * 8 + cf * 4);
            *(f32x4*)(lds + bl * 132 + cf * 4) = v;   // coalesced read
        }
        __syncthreads();
        for (int c = t; c < 1024; c += 256) {
            const int i_l = c >> 6, b_l = c & 63;
            const float* r = lds + b_l * 132 + i_l * 8;
            uint4 o;
            o.x = f2bf(r[0]) | (f2bf(r[1]) << 16);
            o.y = f2bf(r[2]) | (f2bf(r[3]) << 16);
            o.z = f2bf(r[4]) | (f2bf(r[5]) << 16);
            o.w = f2bf(r[6]) | (f2bf(r[7]) << 16);
            ((uint4*)xhu)[(size_t)(i0 + i_l) * 256 + b0 + b_l] = o;  // 1KB runs
        }
    }
}

// ------------- routing pass: 512 thr, 32 b, W staged once -------------
template<int PASS>
__global__ __launch_bounds__(THREADS, 2)
void caps_pass(const unsigned short* __restrict__ wht,
               const unsigned short* __restrict__ xht,
               const float* __restrict__ sp0,   // s_sum of pass0 (P>=1)
               const float* __restrict__ sp1,   // s_sum of pass1 (P==2)
               float* __restrict__ s_cur,       // accumulate here
               float* __restrict__ s_next) {    // zero for next pass (P<2)
    __shared__ __align__(16) unsigned char smem[SMEM_B];
    unsigned short* wsl = (unsigned short*)smem;              // [12][160][8]
    unsigned short* xsl = (unsigned short*)(smem + XSL_OFF_B);// [12][32][8]
    float* red = (float*)smem;   // 4 regions x 16*REDS = 41,984 B (aliased)
    float* vdl = (float*)smem;   // 32*REDS*4 = 20,992 B (aliased, pre-W)

    const int t = threadIdx.x;
    const int l = t & 63;
    const int w = t >> 6;              // wave 0..7
    const int h = w >> 2;              // half: 16-batch subtile
    const int r = w & 3;               // i-quarter: 3 i each
    const int m = l & 15;              // b in subtile / A-row / C-col
    const int q = l >> 4;              // k-quad (replicated) / d-quad (out)
    const int islab = blockIdx.x;      // 0..95
    const int b0 = blockIdx.y * BPB;   // b-group of 32
    const int bg = b0 + h * 16 + m;
    const int i0 = islab * IPB;

    // ---- stage x slab: 12 i x 32 b (xsl disjoint from vdl) ----
    {
        uint4* dX = (uint4*)xsl;
        for (int c = t; c < IPB * BPB; c += THREADS) {
            const int il = c >> 5, bl = c & 31;
            dX[c] = ((const uint4*)xht)[(size_t)(i0 + il) * 256 + b0 + bl];
        }
    }

    // ---- zero next pass's s_sum (islab==0 blocks; visible at boundary) ----
    if (PASS < 2 && islab == 0) {
        for (int c = t; c < BPB * JD; c += THREADS) {
            const int jd = c >> 5, bl = c & 31;
            s_next[jd * 256 + b0 + bl] = 0.f;
        }
    }

    // ---- P>0 preamble: redundant squash of 32 batches -> vdl -> vd regs ----
    f32x4 vd[10];
    if (PASS > 0) {
        const int b_l = t >> 4, dd = t & 15;   // 32 x 16 == 512 threads
        #pragma unroll
        for (int jj = 0; jj < 10; ++jj) {
            float sv = sp0[(jj * 16 + dd) * 256 + b0 + b_l];
            float tt = sv * sv;
            tt += __shfl_xor(tt, 1);
            tt += __shfl_xor(tt, 2);
            tt += __shfl_xor(tt, 4);
            tt += __shfl_xor(tt, 8);
            float vv = (tt / (1.0f + tt) / sqrtf(tt + 1e-7f)) * sv;
            if (PASS == 2) {
                float s1 = sp1[(jj * 16 + dd) * 256 + b0 + b_l];
                float t1 = s1 * s1;
                t1 += __shfl_xor(t1, 1);
                t1 += __shfl_xor(t1, 2);
                t1 += __shfl_xor(t1, 4);
                t1 += __shfl_xor(t1, 8);
                vv += (t1 / (1.0f + t1) / sqrtf(t1 + 1e-7f)) * s1;
            }
            vdl[b_l * REDS + jj * 16 + dd] = vv;
        }
        __syncthreads();
        #pragma unroll
        for (int jt = 0; jt < 10; ++jt)
            vd[jt] = *(const f32x4*)(vdl + (h * 16 + m) * REDS + jt * 16 + q * 4);
    }
    __syncthreads();   // vdl reads done -> wsl region reusable (all PASSes)

    // ---- stage W slab: 12 i x 160 uint4, coalesced, ONCE per block ----
    {
        const uint4* srcW = (const uint4*)wht + (size_t)i0 * 160;
        uint4* dW = (uint4*)wsl;
        for (int c = t; c < IPB * 160; c += THREADS) dW[c] = srcW[c];
    }
    __syncthreads();   // wsl + xsl ready

    f32x4 s[10];
    #pragma unroll
    for (int jt = 0; jt < 10; ++jt) s[jt] = (f32x4){0.f, 0.f, 0.f, 0.f};

    #pragma unroll 1
    for (int ii = 0; ii < 3; ++ii) {
        const int il = r * 3 + ii;                 // 0..11
        const bf16x8 xb = *(const bf16x8*)(xsl + (il * BPB + h * 16 + m) * 8);

        if (PASS == 0) {
            #pragma unroll
            for (int jt = 0; jt < 10; ++jt) {
                const bf16x8 af = *(const bf16x8*)(wsl + (il * 160 + jt * 16 + m) * 8);
                s[jt] = __builtin_amdgcn_mfma_f32_16x16x32_bf16(af, xb, s[jt], 0, 0, 0);
            }
        } else {
            f32x4 u[10];
            #pragma unroll
            for (int jt = 0; jt < 10; ++jt) {
                const bf16x8 af = *(const bf16x8*)(wsl + (il * 160 + jt * 16 + m) * 8);
                u[jt] = __builtin_amdgcn_mfma_f32_16x16x32_bf16(
                            af, xb, (f32x4){0.f, 0.f, 0.f, 0.f}, 0, 0, 0);
            }
            float L[10];
            #pragma unroll
            for (int jt = 0; jt < 10; ++jt) {
                const f32x4 p = vd[jt] * u[jt];
                float e = (p.x + p.y) + (p.z + p.w);
                e += __shfl_xor(e, 16);
                e += __shfl_xor(e, 32);
                L[jt] = e;
            }
            float Z = 0.f;
            #pragma unroll
            for (int jt = 0; jt < 10; ++jt) { L[jt] = __expf(L[jt]); Z += L[jt]; }
            const float inv = 1.0f / Z;
            #pragma unroll
            for (int jt = 0; jt < 10; ++jt) s[jt] += (L[jt] * inv) * u[jt];
        }
    }

    if (PASS == 0) {
        #pragma unroll
        for (int jt = 0; jt < 10; ++jt) s[jt] *= 0.1f;
    }

    // ---- per-half 4-wave tree reduce (red aliases wsl+xsl) ----
    __syncthreads();
    if (r >= 2) {
        float* rp = red + (h * 2 + (r - 2)) * (16 * REDS) + m * REDS + q * 4;
        #pragma unroll
        for (int jt = 0; jt < 10; ++jt) *(f32x4*)(rp + jt * 16) = s[jt];
    }
    __syncthreads();
    if (r < 2) {
        const float* rp = red + (h * 2 + r) * (16 * REDS) + m * REDS + q * 4;
        #pragma unroll
        for (int jt = 0; jt < 10; ++jt) s[jt] += *(const f32x4*)(rp + jt * 16);
    }
    __syncthreads();
    if (r == 1) {
        float* rp = red + (h * 2) * (16 * REDS) + m * REDS + q * 4;
        #pragma unroll
        for (int jt = 0; jt < 10; ++jt) *(f32x4*)(rp + jt * 16) = s[jt];
    }
    __syncthreads();
    if (r == 0) {
        const float* rp = red + (h * 2) * (16 * REDS) + m * REDS + q * 4;
        #pragma unroll
        for (int jt = 0; jt < 10; ++jt) s[jt] += *(const f32x4*)(rp + jt * 16);
        // memory-side device-scope atomics; [jd][b] -> 16-consecutive per quad
        #pragma unroll
        for (int jt = 0; jt < 10; ++jt) {
            atomicAdd(&s_cur[(jt * 16 + q * 4 + 0) * 256 + bg], s[jt].x);
            atomicAdd(&s_cur[(jt * 16 + q * 4 + 1) * 256 + bg], s[jt].y);
            atomicAdd(&s_cur[(jt * 16 + q * 4 + 2) * 256 + bg], s[jt].z);
            atomicAdd(&s_cur[(jt * 16 + q * 4 + 3) * 256 + bg], s[jt].w);
        }
    }
}

// ---------------- final squash: s_sum2 -> out ----------------
__global__ __launch_bounds__(256)
void sq_final(const float* __restrict__ s2, float* __restrict__ out) {
    const int bid = blockIdx.x;        // 0..159
    const int t = threadIdx.x;
    const int j = bid % 10, b_hi = bid / 10;
    const int b = b_hi * 16 + (t >> 4);
    const int d = t & 15;
    const float sv = s2[(j * 16 + d) * 256 + b];
    float tt = sv * sv;
    tt += __shfl_xor(tt, 1);
    tt += __shfl_xor(tt, 2);
    tt += __shfl_xor(tt, 4);
    tt += __shfl_xor(tt, 8);
    const float sc = tt / (1.0f + tt) / sqrtf(tt + 1e-7f);
    out[b * JD + j * 16 + d] = sc * sv;
}

// ---------- fallback: round-1 fused kernel (ws too small; shouldn't happen) ----------
#define FB_NGROUPS 32
#define FB_THREADS (FB_NGROUPS * 16)
#define FB_ITERS (IN_CAPS / FB_NGROUPS)
__global__ __launch_bounds__(FB_THREADS)
void caps_routing_kernel(const float* __restrict__ x, const float* __restrict__ W,
                         float* __restrict__ out) {
    __shared__ __align__(16) float xsf[IN_CAPS * 8];
    __shared__ float sredf[FB_NGROUPS * JD];
    __shared__ float vdot_lds[JD];
    const int b = blockIdx.x, tid = threadIdx.x;
    const int g = tid >> 4, d = tid & 15;
    {
        const float4* xg = reinterpret_cast<const float4*>(x + (size_t)b * IN_CAPS * 8);
        float4* xl = reinterpret_cast<float4*>(xsf);
        for (int t = tid; t < IN_CAPS * 2; t += FB_THREADS) xl[t] = xg[t];
    }
    __syncthreads();
    for (int pass = 0; pass < 3; ++pass) {
        float vdot_reg[OUT_CAPS];
        if (pass > 0) {
            #pragma unroll
            for (int j = 0; j < OUT_CAPS; ++j) vdot_reg[j] = vdot_lds[j * 16 + d];
        }
        float s_loc[OUT_CAPS];
        #pragma unroll
        for (int j = 0; j < OUT_CAPS; ++j) s_loc[j] = 0.f;
        for (int it = 0; it < FB_ITERS; ++it) {
            const int i = it * FB_NGROUPS + g;
            float xk[8];
            {
                const float4* xr = reinterpret_cast<const float4*>(xsf + i * 8);
                float4 a0 = xr[0], a1 = xr[1];
                xk[0]=a0.x; xk[1]=a0.y; xk[2]=a0.z; xk[3]=a0.w;
                xk[4]=a1.x; xk[5]=a1.y; xk[6]=a1.z; xk[7]=a1.w;
            }
            const float* wpf = W + (size_t)i * 1280 + d;
            float u[OUT_CAPS];
            #pragma unroll
            for (int j = 0; j < OUT_CAPS; ++j) {
                float acc = 0.f;
                #pragma unroll
                for (int k = 0; k < 8; ++k) acc = fmaf(xk[k], wpf[j * 128 + k * 16], acc);
                u[j] = acc;
            }
            if (pass == 0) {
                #pragma unroll
                for (int j = 0; j < OUT_CAPS; ++j) s_loc[j] = fmaf(0.1f, u[j], s_loc[j]);
            } else {
                float logit[OUT_CAPS];
                #pragma unroll
                for (int j = 0; j < OUT_CAPS; ++j) {
                    float t2 = vdot_reg[j] * u[j];
                    t2 += __shfl_xor(t2, 1); t2 += __shfl_xor(t2, 2);
                    t2 += __shfl_xor(t2, 4); t2 += __shfl_xor(t2, 8);
                    logit[j] = t2;
                }
                float mm = logit[0];
                #pragma unroll
                for (int j = 1; j < OUT_CAPS; ++j) mm = fmaxf(mm, logit[j]);
                float Z = 0.f, e[OUT_CAPS];
                #pragma unroll
                for (int j = 0; j < OUT_CAPS; ++j) { e[j] = expf(logit[j] - mm); Z += e[j]; }
                const float invZ = 1.0f / Z;
                #pragma unroll
                for (int j = 0; j < OUT_CAPS; ++j) s_loc[j] = fmaf(e[j] * invZ, u[j], s_loc[j]);
            }
        }
        #pragma unroll
        for (int j = 0; j < OUT_CAPS; ++j) sredf[g * JD + j * 16 + d] = s_loc[j];
        __syncthreads();
        if (tid < JD) {
            float sv = 0.f;
            #pragma unroll 8
            for (int gg = 0; gg < FB_NGROUPS; ++gg) sv += sredf[gg * JD + tid];
            float t2 = sv * sv;
            t2 += __shfl_xor(t2, 1); t2 += __shfl_xor(t2, 2);
            t2 += __shfl_xor(t2, 4); t2 += __shfl_xor(t2, 8);
            const float scale = t2 / (1.0f + t2) / sqrtf(t2 + 1e-7f);
            const float v = scale * sv;
            if (pass == 2) out[(size_t)b * JD + tid] = v;
            else vdot_lds[tid] = (pass == 0) ? v : (vdot_lds[tid] + v);
        }
        __syncthreads();
    }
}

extern "C" void kernel_launch(void* const* d_in, const int* in_sizes, int n_in,
                              void* d_out, int out_size, void* d_ws, size_t ws_size,
                              hipStream_t stream) {
    const float* x = (const float*)d_in[0];
    const float* W = (const float*)d_in[1];
    float* out = (float*)d_out;

    if (ws_size >= WS_NEED) {
        unsigned short* wht = (unsigned short*)d_ws;
        unsigned short* xht = (unsigned short*)((char*)d_ws + WHT_BYTES);
        float* s0 = (float*)((char*)d_ws + WHT_BYTES + XHT_BYTES);
        float* s1 = (float*)((char*)d_ws + WHT_BYTES + XHT_BYTES + SSUM_BYTES);
        float* s2 = (float*)((char*)d_ws + WHT_BYTES + XHT_BYTES + 2 * SSUM_BYTES);

        prep_all<<<PREPW_BLOCKS + PREPX_BLOCKS, 256, 0, stream>>>(
            x, W, (unsigned*)wht, (unsigned*)xht, s0);

        const dim3 gR(NSLAB, B_TOT / BPB);   // (96, 8)
        caps_pass<0><<<gR, THREADS, 0, stream>>>(wht, xht, nullptr, nullptr, s0, s1);
        caps_pass<1><<<gR, THREADS, 0, stream>>>(wht, xht, s0, nullptr, s1, s2);
        caps_pass<2><<<gR, THREADS, 0, stream>>>(wht, xht, s0, s1, s2, nullptr);
        sq_final<<<160, 256, 0, stream>>>(s2, out);
    } else {
        caps_routing_kernel<<<B_TOT, FB_THREADS, 0, stream>>>(x, W, out);
    }
}

// Round 20
// 70.006 us; speedup vs baseline: 1.7050x; 1.7050x over previous
//
#include <hip/hip_runtime.h>
#include <math.h>

// CapsuleLayer dynamic routing. B=256, IN=1152, K=8, J=10, D=16, 3 passes.
//
// ===== ROUND-14 CHAMPION, byte-exact revert (measured 70.09 us, passed) =====
// 5 kernels; global reduction via device-scope memory-side f32 atomicAdd
// (r12-r14 lesson: grid.sync ~100us/sync, threadfence ~50us/pass, UC-atomic
// slabs ~30us/pass; kernel boundary + memory-side atomicAdd are cheap):
//  prep_all : (r7-r14-verified) W -> wht bf16 [i][jd][k]*0.25 (k-replication
//             trick: 4 K-quads read the same 8-k fragment -> u = 4*(x*W/4));
//             x -> xht bf16 [i][b][k]. Zeroes s_sum0.
//  caps_pass<P>: grid (48 i-slabs x 16 b-tiles), 256 thr = 4 waves.
//             NSLAB*IPB = 48*24 = 1152 = IN_CAPS. P>0 preamble: block
//             redundantly squashes s_sum (L2-hit) for its 16 batches ->
//             vdot (16-lane shfl; P2 adds v0+v1). Then r11-verified compute
//             (MFMA fragment math, in-lane softmax without max-sub, 4-wave
//             LDS tree reduce). w==0 atomicAdds partial s into s_sum[jd][b]
//             (16-consecutive per quad). islab==0 zeroes the NEXT s_sum.
//  sq_final : squash s_sum2 -> out.
// Failed perturbations (keep for the record): r16 (256,4)->VGPR 64 spill;
// r17 96 slabs -> per-block fixed costs x2; r18 (512,4)-> spill;
// r19 512thr/(512,2) -> 8-wave barrier cost. This config is the optimum.
// FP-atomic order varies run-to-run (~1e-6) — tolerance-validated.
// Algebra: logits at pass t = (sum of previous v)·u_hat; pass 0 c = 0.1.

typedef float f32x4 __attribute__((ext_vector_type(4)));
typedef short bf16x8 __attribute__((ext_vector_type(8)));

#define B_TOT 256
#define IN_CAPS 1152
#define OUT_CAPS 10
#define JD 160

#define NSLAB 48
#define IPB 24             // i per block  (NSLAB*IPB == IN_CAPS)
#define CHI 12             // i per W chunk (2 chunks)
#define REDS 164

#define WHT_BYTES (1152ull * 160 * 8 * 2)             // 2,949,120
#define XHT_BYTES (1152ull * 256 * 8 * 2)             // 4,718,592
#define SSUM_BYTES ((size_t)B_TOT * JD * 4)           // 163,840
#define WS_NEED   (WHT_BYTES + XHT_BYTES + 3 * SSUM_BYTES)

static __device__ __forceinline__ unsigned f2bf(float f) {
    unsigned u = __float_as_uint(f);
    return (u + 0x7FFFu + ((u >> 16) & 1u)) >> 16;
}

// ---------------- coalesced preps (r7-r14-verified) ----------------
#define PREPW_BLOCKS 288   // 4 i each
#define PREPX_BLOCKS 288   // 16 i x 64 b each

__global__ __launch_bounds__(256)
void prep_all(const float* __restrict__ x, const float* __restrict__ W,
              unsigned* __restrict__ whu, unsigned* __restrict__ xhu,
              float* __restrict__ s0) {
    __shared__ __align__(16) float lds[64 * 132];   // 33,792 B
    const int bid = blockIdx.x, t = threadIdx.x;

    if (bid < 160) s0[bid * 256 + t] = 0.f;         // zero s_sum0 (replay-safe)

    if (bid < PREPW_BLOCKS) {
        const int i0 = bid * 4;
        const f32x4* src = (const f32x4*)(W + (size_t)i0 * 1280);
        for (int c = t; c < 1280; c += 256)
            *(f32x4*)(lds + c * 4) = src[c];          // coalesced read
        __syncthreads();
        for (int c = t; c < 2560; c += 256) {
            const int i_l = c / 640, p = c % 640;
            const int jd = p >> 2, kp = p & 3;        // k = 2*kp
            const int j = jd >> 4, d = jd & 15;
            const float* base = lds + i_l * 1280 + j * 128 + d;
            const unsigned lo = f2bf(base[(2 * kp) * 16] * 0.25f);
            const unsigned hi = f2bf(base[(2 * kp + 1) * 16] * 0.25f);
            whu[(size_t)i0 * 640 + c] = lo | (hi << 16);   // coalesced write
        }
    } else {
        const int bx = bid - PREPW_BLOCKS;
        const int it = bx >> 2;          // 72 i-tiles
        const int bt = bx & 3;           // 4 b-tiles of 64
        const int i0 = it * 16, b0 = bt * 64;
        for (int c = t; c < 2048; c += 256) {
            const int bl = c >> 5, cf = c & 31;
            f32x4 v = *(const f32x4*)(x + (size_t)(b0 + bl) * 9216 + i0 * 8 + cf * 4);
            *(f32x4*)(lds + bl * 132 + cf * 4) = v;   // coalesced read
        }
        __syncthreads();
        for (int c = t; c < 1024; c += 256) {
            const int i_l = c >> 6, b_l = c & 63;
            const float* r = lds + b_l * 132 + i_l * 8;
            uint4 o;
            o.x = f2bf(r[0]) | (f2bf(r[1]) << 16);
            o.y = f2bf(r[2]) | (f2bf(r[3]) << 16);
            o.z = f2bf(r[4]) | (f2bf(r[5]) << 16);
            o.w = f2bf(r[6]) | (f2bf(r[7]) << 16);
            ((uint4*)xhu)[(size_t)(i0 + i_l) * 256 + b0 + b_l] = o;  // 1KB runs
        }
    }
}

// ---------------- routing pass, atomicAdd-fused ----------------
// s_sum layout: [jd][b] (jd = j*16+d major) -> wave atomics hit 16
// consecutive addresses per (jt, q, component).
template<int PASS>
__global__ __launch_bounds__(256, 3)
void caps_pass(const unsigned short* __restrict__ wht,
               const unsigned short* __restrict__ xht,
               const float* __restrict__ sp0,   // s_sum of pass0 (P>=1)
               const float* __restrict__ sp1,   // s_sum of pass1 (P==2)
               float* __restrict__ s_cur,       // accumulate here
               float* __restrict__ s_next) {    // zero for next pass (P<2)
    __shared__ __align__(16) unsigned short wsl[CHI * 160 * 8];  // 30,720 B
    __shared__ __align__(16) unsigned short xsl[IPB * 16 * 8];   //  6,144 B
    float* red = (float*)wsl;   // aliased: vdl (preamble) + tree reduce
    float* vdl = (float*)wsl;   // 16 x REDS floats = 10,496 B

    const int t = threadIdx.x;
    const int l = t & 63;
    const int w = t >> 6;              // wave 0..3 (splits i)
    const int m = l & 15;              // b in tile / A-row / C-col
    const int q = l >> 4;              // k-quad (replicated) / d-quad (out)
    const int islab = blockIdx.x;      // 0..47
    const int btile = blockIdx.y;      // 0..15
    const int b0 = btile * 16;
    const int i0 = islab * IPB;

    // ---- stage x slab once: 24 i x 16 b ----
    {
        uint4* dX = (uint4*)xsl;
        for (int c = t; c < IPB * 16; c += 256) {
            const int il = c >> 4, bl = c & 15;
            dX[c] = ((const uint4*)xht)[(size_t)(i0 + il) * 256 + b0 + bl];
        }
    }

    // ---- zero next pass's s_sum (islab==0 blocks; visible at boundary) ----
    if (PASS < 2 && islab == 0) {
        for (int c = t; c < 2560; c += 256) {
            const int jd = c >> 4, bl = c & 15;
            s_next[jd * 256 + b0 + bl] = 0.f;
        }
    }

    // ---- P>0 preamble: redundant per-block squash -> vdl -> vd regs ----
    f32x4 vd[10];
    if (PASS > 0) {
        const int b_l = t >> 4, dd = t & 15;
        #pragma unroll
        for (int jj = 0; jj < 10; ++jj) {
            float sv = sp0[(jj * 16 + dd) * 256 + b0 + b_l];
            float tt = sv * sv;
            tt += __shfl_xor(tt, 1);
            tt += __shfl_xor(tt, 2);
            tt += __shfl_xor(tt, 4);
            tt += __shfl_xor(tt, 8);
            float vv = (tt / (1.0f + tt) / sqrtf(tt + 1e-7f)) * sv;
            if (PASS == 2) {
                float s1 = sp1[(jj * 16 + dd) * 256 + b0 + b_l];
                float t1 = s1 * s1;
                t1 += __shfl_xor(t1, 1);
                t1 += __shfl_xor(t1, 2);
                t1 += __shfl_xor(t1, 4);
                t1 += __shfl_xor(t1, 8);
                vv += (t1 / (1.0f + t1) / sqrtf(t1 + 1e-7f)) * s1;
            }
            vdl[b_l * REDS + jj * 16 + dd] = vv;
        }
        __syncthreads();
        #pragma unroll
        for (int jt = 0; jt < 10; ++jt)
            vd[jt] = *(const f32x4*)(vdl + m * REDS + jt * 16 + q * 4);
    }

    f32x4 s[10];
    #pragma unroll
    for (int jt = 0; jt < 10; ++jt) s[jt] = (f32x4){0.f, 0.f, 0.f, 0.f};

    // ---- 2 W chunks of 12 i ----
    #pragma unroll 1
    for (int ch = 0; ch < 2; ++ch) {
        __syncthreads();    // vdl dead / prev chunk reads done / xsl ordered
        {
            const uint4* srcW = (const uint4*)wht + (size_t)(i0 + ch * CHI) * 160;
            uint4* dW = (uint4*)wsl;
            for (int c = t; c < CHI * 160; c += 256) dW[c] = srcW[c];
        }
        __syncthreads();

        #pragma unroll 1
        for (int ii = 0; ii < 3; ++ii) {
            const int il = w * 3 + ii;                 // 0..11 within chunk
            const bf16x8 xb = *(const bf16x8*)(xsl + ((ch * CHI + il) * 16 + m) * 8);

            if (PASS == 0) {
                #pragma unroll
                for (int jt = 0; jt < 10; ++jt) {
                    const bf16x8 af = *(const bf16x8*)(wsl + (il * 160 + jt * 16 + m) * 8);
                    s[jt] = __builtin_amdgcn_mfma_f32_16x16x32_bf16(af, xb, s[jt], 0, 0, 0);
                }
            } else {
                f32x4 u[10];
                #pragma unroll
                for (int jt = 0; jt < 10; ++jt) {
                    const bf16x8 af = *(const bf16x8*)(wsl + (il * 160 + jt * 16 + m) * 8);
                    u[jt] = __builtin_amdgcn_mfma_f32_16x16x32_bf16(
                                af, xb, (f32x4){0.f, 0.f, 0.f, 0.f}, 0, 0, 0);
                }
                float L[10];
                #pragma unroll
                for (int jt = 0; jt < 10; ++jt) {
                    const f32x4 p = vd[jt] * u[jt];
                    float e = (p.x + p.y) + (p.z + p.w);
                    e += __shfl_xor(e, 16);
                    e += __shfl_xor(e, 32);
                    L[jt] = e;
                }
                float Z = 0.f;
                #pragma unroll
                for (int jt = 0; jt < 10; ++jt) { L[jt] = __expf(L[jt]); Z += L[jt]; }
                const float inv = 1.0f / Z;
                #pragma unroll
                for (int jt = 0; jt < 10; ++jt) s[jt] += (L[jt] * inv) * u[jt];
            }
        }
    }

    if (PASS == 0) {
        #pragma unroll
        for (int jt = 0; jt < 10; ++jt) s[jt] *= 0.1f;
    }

    // ---- 4-wave tree reduce through LDS (red aliases wsl) ----
    __syncthreads();
    if (w >= 2) {
        float* rp = red + (w - 2) * (16 * REDS) + m * REDS + q * 4;
        #pragma unroll
        for (int jt = 0; jt < 10; ++jt) *(f32x4*)(rp + jt * 16) = s[jt];
    }
    __syncthreads();
    if (w < 2) {
        const float* rp = red + w * (16 * REDS) + m * REDS + q * 4;
        #pragma unroll
        for (int jt = 0; jt < 10; ++jt) s[jt] += *(const f32x4*)(rp + jt * 16);
    }
    __syncthreads();
    if (w == 1) {
        float* rp = red + m * REDS + q * 4;
        #pragma unroll
        for (int jt = 0; jt < 10; ++jt) *(f32x4*)(rp + jt * 16) = s[jt];
    }
    __syncthreads();
    if (w == 0) {
        const float* rp = red + m * REDS + q * 4;
        #pragma unroll
        for (int jt = 0; jt < 10; ++jt) s[jt] += *(const f32x4*)(rp + jt * 16);
        // memory-side device-scope atomics; [jd][b] -> 16-consecutive per quad
        #pragma unroll
        for (int jt = 0; jt < 10; ++jt) {
            atomicAdd(&s_cur[(jt * 16 + q * 4 + 0) * 256 + b0 + m], s[jt].x);
            atomicAdd(&s_cur[(jt * 16 + q * 4 + 1) * 256 + b0 + m], s[jt].y);
            atomicAdd(&s_cur[(jt * 16 + q * 4 + 2) * 256 + b0 + m], s[jt].z);
            atomicAdd(&s_cur[(jt * 16 + q * 4 + 3) * 256 + b0 + m], s[jt].w);
        }
    }
}

// ---------------- final squash: s_sum2 -> out ----------------
__global__ __launch_bounds__(256)
void sq_final(const float* __restrict__ s2, float* __restrict__ out) {
    const int bid = blockIdx.x;        // 0..159
    const int t = threadIdx.x;
    const int j = bid % 10, b_hi = bid / 10;
    const int b = b_hi * 16 + (t >> 4);
    const int d = t & 15;
    const float sv = s2[(j * 16 + d) * 256 + b];
    float tt = sv * sv;
    tt += __shfl_xor(tt, 1);
    tt += __shfl_xor(tt, 2);
    tt += __shfl_xor(tt, 4);
    tt += __shfl_xor(tt, 8);
    const float sc = tt / (1.0f + tt) / sqrtf(tt + 1e-7f);
    out[b * JD + j * 16 + d] = sc * sv;
}

// ---------- fallback: round-1 fused kernel (ws too small; shouldn't happen) ----------
#define FB_NGROUPS 32
#define FB_THREADS (FB_NGROUPS * 16)
#define FB_ITERS (IN_CAPS / FB_NGROUPS)
__global__ __launch_bounds__(FB_THREADS)
void caps_routing_kernel(const float* __restrict__ x, const float* __restrict__ W,
                         float* __restrict__ out) {
    __shared__ __align__(16) float xsf[IN_CAPS * 8];
    __shared__ float sredf[FB_NGROUPS * JD];
    __shared__ float vdot_lds[JD];
    const int b = blockIdx.x, tid = threadIdx.x;
    const int g = tid >> 4, d = tid & 15;
    {
        const float4* xg = reinterpret_cast<const float4*>(x + (size_t)b * IN_CAPS * 8);
        float4* xl = reinterpret_cast<float4*>(xsf);
        for (int t = tid; t < IN_CAPS * 2; t += FB_THREADS) xl[t] = xg[t];
    }
    __syncthreads();
    for (int pass = 0; pass < 3; ++pass) {
        float vdot_reg[OUT_CAPS];
        if (pass > 0) {
            #pragma unroll
            for (int j = 0; j < OUT_CAPS; ++j) vdot_reg[j] = vdot_lds[j * 16 + d];
        }
        float s_loc[OUT_CAPS];
        #pragma unroll
        for (int j = 0; j < OUT_CAPS; ++j) s_loc[j] = 0.f;
        for (int it = 0; it < FB_ITERS; ++it) {
            const int i = it * FB_NGROUPS + g;
            float xk[8];
            {
                const float4* xr = reinterpret_cast<const float4*>(xsf + i * 8);
                float4 a0 = xr[0], a1 = xr[1];
                xk[0]=a0.x; xk[1]=a0.y; xk[2]=a0.z; xk[3]=a0.w;
                xk[4]=a1.x; xk[5]=a1.y; xk[6]=a1.z; xk[7]=a1.w;
            }
            const float* wpf = W + (size_t)i * 1280 + d;
            float u[OUT_CAPS];
            #pragma unroll
            for (int j = 0; j < OUT_CAPS; ++j) {
                float acc = 0.f;
                #pragma unroll
                for (int k = 0; k < 8; ++k) acc = fmaf(xk[k], wpf[j * 128 + k * 16], acc);
                u[j] = acc;
            }
            if (pass == 0) {
                #pragma unroll
                for (int j = 0; j < OUT_CAPS; ++j) s_loc[j] = fmaf(0.1f, u[j], s_loc[j]);
            } else {
                float logit[OUT_CAPS];
                #pragma unroll
                for (int j = 0; j < OUT_CAPS; ++j) {
                    float t2 = vdot_reg[j] * u[j];
                    t2 += __shfl_xor(t2, 1); t2 += __shfl_xor(t2, 2);
                    t2 += __shfl_xor(t2, 4); t2 += __shfl_xor(t2, 8);
                    logit[j] = t2;
                }
                float mm = logit[0];
                #pragma unroll
                for (int j = 1; j < OUT_CAPS; ++j) mm = fmaxf(mm, logit[j]);
                float Z = 0.f, e[OUT_CAPS];
                #pragma unroll
                for (int j = 0; j < OUT_CAPS; ++j) { e[j] = expf(logit[j] - mm); Z += e[j]; }
                const float invZ = 1.0f / Z;
                #pragma unroll
                for (int j = 0; j < OUT_CAPS; ++j) s_loc[j] = fmaf(e[j] * invZ, u[j], s_loc[j]);
            }
        }
        #pragma unroll
        for (int j = 0; j < OUT_CAPS; ++j) sredf[g * JD + j * 16 + d] = s_loc[j];
        __syncthreads();
        if (tid < JD) {
            float sv = 0.f;
            #pragma unroll 8
            for (int gg = 0; gg < FB_NGROUPS; ++gg) sv += sredf[gg * JD + tid];
            float t2 = sv * sv;
            t2 += __shfl_xor(t2, 1); t2 += __shfl_xor(t2, 2);
            t2 += __shfl_xor(t2, 4); t2 += __shfl_xor(t2, 8);
            const float scale = t2 / (1.0f + t2) / sqrtf(t2 + 1e-7f);
            const float v = scale * sv;
            if (pass == 2) out[(size_t)b * JD + tid] = v;
            else vdot_lds[tid] = (pass == 0) ? v : (vdot_lds[tid] + v);
        }
        __syncthreads();
    }
}

extern "C" void kernel_launch(void* const* d_in, const int* in_sizes, int n_in,
                              void* d_out, int out_size, void* d_ws, size_t ws_size,
                              hipStream_t stream) {
    const float* x = (const float*)d_in[0];
    const float* W = (const float*)d_in[1];
    float* out = (float*)d_out;

    if (ws_size >= WS_NEED) {
        unsigned short* wht = (unsigned short*)d_ws;
        unsigned short* xht = (unsigned short*)((char*)d_ws + WHT_BYTES);
        float* s0 = (float*)((char*)d_ws + WHT_BYTES + XHT_BYTES);
        float* s1 = (float*)((char*)d_ws + WHT_BYTES + XHT_BYTES + SSUM_BYTES);
        float* s2 = (float*)((char*)d_ws + WHT_BYTES + XHT_BYTES + 2 * SSUM_BYTES);

        prep_all<<<PREPW_BLOCKS + PREPX_BLOCKS, 256, 0, stream>>>(
            x, W, (unsigned*)wht, (unsigned*)xht, s0);

        const dim3 gR(NSLAB, 16);
        caps_pass<0><<<gR, 256, 0, stream>>>(wht, xht, nullptr, nullptr, s0, s1);
        caps_pass<1><<<gR, 256, 0, stream>>>(wht, xht, s0, nullptr, s1, s2);
        caps_pass<2><<<gR, 256, 0, stream>>>(wht, xht, s0, s1, s2, nullptr);
        sq_final<<<160, 256, 0, stream>>>(s2, out);
    } else {
        caps_routing_kernel<<<B_TOT, FB_THREADS, 0, stream>>>(x, W, out);
    }
}